// Round 4
// baseline (1320.405 us; speedup 1.0000x reference)
//
#include <hip/hip_runtime.h>
#include <hip/hip_bf16.h>
#include <stdint.h>

#define BT   16384   // B*T
#define TT   4096    // T
#define NB   4       // B
#define DD   1024
#define RR   128
#define DFFC 4096

typedef __bf16 bf16_8 __attribute__((ext_vector_type(8)));
typedef float  f32x4  __attribute__((ext_vector_type(4)));

__device__ __forceinline__ void async16(const void* g, void* l) {
  __builtin_amdgcn_global_load_lds((__attribute__((address_space(1))) void*)(g),
                                   (__attribute__((address_space(3))) void*)(l),
                                   16, 0, 0);
}

// ---------------- fp32 -> bf16 convert ----------------
__global__ __launch_bounds__(256) void cvt_k(const float* __restrict__ src,
                                             __hip_bfloat16* __restrict__ dst, int n4) {
  const int i = blockIdx.x * 256 + threadIdx.x;
  if (i >= n4) return;
  const float4 v = ((const float4*)src)[i];
  __hip_bfloat16* o = dst + (size_t)i * 4;
  o[0] = __float2bfloat16(v.x);
  o[1] = __float2bfloat16(v.y);
  o[2] = __float2bfloat16(v.z);
  o[3] = __float2bfloat16(v.w);
}

// ---------------- RMSNorm (fp32 in, bf16 out) ----------------
__global__ __launch_bounds__(256) void rmsnorm_k(const float* __restrict__ x,
                                                 const float* __restrict__ wgt,
                                                 __hip_bfloat16* __restrict__ out) {
  const int row = blockIdx.x;
  const int t = threadIdx.x;
  const float4 v = ((const float4*)(x + (size_t)row * DD))[t];
  float ss = v.x*v.x + v.y*v.y + v.z*v.z + v.w*v.w;
  #pragma unroll
  for (int m = 1; m < 64; m <<= 1) ss += __shfl_xor(ss, m, 64);
  __shared__ float red[4];
  if ((t & 63) == 0) red[t >> 6] = ss;
  __syncthreads();
  ss = red[0] + red[1] + red[2] + red[3];
  const float rms = rsqrtf(ss * (1.0f / DD) + 1e-6f);
  const float4 wv = ((const float4*)wgt)[t];
  __hip_bfloat16* o = out + (size_t)row * DD + t * 4;
  o[0] = __float2bfloat16(v.x * rms * wv.x);
  o[1] = __float2bfloat16(v.y * rms * wv.y);
  o[2] = __float2bfloat16(v.z * rms * wv.z);
  o[3] = __float2bfloat16(v.w * rms * wv.w);
}

// ---------------- RoPE: qkv (M,384) -> qr, kr (M,128) ----------------
__global__ __launch_bounds__(256) void rope_k(const __hip_bfloat16* __restrict__ qkv,
                                              const float* __restrict__ cosb,
                                              const float* __restrict__ sinb,
                                              __hip_bfloat16* __restrict__ qr,
                                              __hip_bfloat16* __restrict__ kr) {
  const int idx = blockIdx.x * 256 + threadIdx.x;  // 0 .. BT*64-1
  const int row = idx >> 6;
  const int i = idx & 63;
  const int tpos = row & (TT - 1);
  const float c = cosb[tpos * 64 + i];
  const float s = sinb[tpos * 64 + i];
  const size_t base = (size_t)row * 384;
  const float q1 = __bfloat162float(qkv[base + i]);
  const float q2 = __bfloat162float(qkv[base + 64 + i]);
  const float k1 = __bfloat162float(qkv[base + 128 + i]);
  const float k2 = __bfloat162float(qkv[base + 192 + i]);
  const size_t ob = (size_t)row * 128;
  qr[ob + i]      = __float2bfloat16( q1 * c + q2 * s);
  qr[ob + 64 + i] = __float2bfloat16(-q1 * s + q2 * c);
  kr[ob + i]      = __float2bfloat16( k1 * c + k2 * s);
  kr[ob + 64 + i] = __float2bfloat16(-k1 * s + k2 * c);
}

// ---------------- V transpose: qkv v-cols -> Vt (B,128,T) ----------------
__global__ __launch_bounds__(256) void vtrans_k(const __hip_bfloat16* __restrict__ qkv,
                                                __hip_bfloat16* __restrict__ Vt) {
  const int b = blockIdx.y, t0 = blockIdx.x * 64, t = threadIdx.x;
  #pragma unroll
  for (int i = 0; i < 4; ++i) {
    const int flat8 = i * 256 + t;       // 0..1023
    const int row = flat8 >> 4;          // 0..63  (t-local)
    const int d8 = (flat8 & 15) * 8;     // dim start
    const bf16_8 v = *(const bf16_8*)&qkv[((size_t)(b * TT + t0 + row)) * 384 + 256 + d8];
    #pragma unroll
    for (int j = 0; j < 8; ++j)
      ((__bf16*)Vt)[((size_t)(b * 128 + d8 + j)) * TT + t0 + row] = v[j];
  }
}

// ---------------- GEMM: C(M,N) = A(M,K) @ Bw(N,K)^T, bf16 MFMA ----------------
// 128^2 tile, 2-barrier loop. Kept for qkv (N=384) and Wo (K=128).
enum { EPI_BF16 = 0, EPI_RESID = 1, EPI_GATE = 2 };

template <int EPI>
__global__ __launch_bounds__(256) void gemm_bt(
    const __hip_bfloat16* __restrict__ A,
    const __hip_bfloat16* __restrict__ Bw,
    const float* __restrict__ resid,
    const __hip_bfloat16* __restrict__ gate,
    __hip_bfloat16* __restrict__ outb,
    float* __restrict__ outf,
    int N, int K) {
  __shared__ __hip_bfloat16 As[128 * 64];
  __shared__ __hip_bfloat16 Bs[128 * 64];
  const int t = threadIdx.x;
  const int w = t >> 6, lane = t & 63;
  const int wm = w >> 1, wn = w & 1;
  const int quad = lane >> 4, l16 = lane & 15;
  const int m0 = blockIdx.y * 128, n0 = blockIdx.x * 128;

  const __hip_bfloat16* Ab = A + (size_t)m0 * K;
  const __hip_bfloat16* Bb = Bw + (size_t)n0 * K;

  const int rloc = w * 8 + (lane >> 3);
  const int c0 = (((lane & 7) ^ ((lane >> 3) & 7)) << 3);
  const int swz = (l16 & 7);

  f32x4 acc[4][4] = {};

  for (int k0 = 0; k0 < K; k0 += 64) {
    #pragma unroll
    for (int j = 0; j < 4; ++j) {
      async16(Ab + (size_t)(j * 32 + rloc) * K + k0 + c0, &As[j * 2048 + w * 512]);
      async16(Bb + (size_t)(j * 32 + rloc) * K + k0 + c0, &Bs[j * 2048 + w * 512]);
    }
    __syncthreads();
    #pragma unroll
    for (int kc = 0; kc < 2; ++kc) {
      bf16_8 af[4], bfr[4];
      #pragma unroll
      for (int i = 0; i < 4; ++i) {
        const int pos = (((kc * 4 + quad) ^ swz) << 3);
        af[i]  = *(const bf16_8*)&As[(wm * 64 + i * 16 + l16) * 64 + pos];
        bfr[i] = *(const bf16_8*)&Bs[(wn * 64 + i * 16 + l16) * 64 + pos];
      }
      #pragma unroll
      for (int mt = 0; mt < 4; ++mt) {
        #pragma unroll
        for (int nt = 0; nt < 4; ++nt)
          acc[mt][nt] = __builtin_amdgcn_mfma_f32_16x16x32_bf16(af[mt], bfr[nt], acc[mt][nt], 0, 0, 0);
      }
    }
    __syncthreads();
  }

  #pragma unroll
  for (int mt = 0; mt < 4; ++mt) {
    #pragma unroll
    for (int nt = 0; nt < 4; ++nt) {
      #pragma unroll
      for (int r = 0; r < 4; ++r) {
        const int row = m0 + wm * 64 + mt * 16 + quad * 4 + r;
        const int col = n0 + wn * 64 + nt * 16 + l16;
        const size_t idx = (size_t)row * N + col;
        const float v = acc[mt][nt][r];
        if (EPI == EPI_BF16) {
          outb[idx] = __float2bfloat16(v);
        } else if (EPI == EPI_RESID) {
          outf[idx] = resid[idx] + v;
        } else {
          const float sv = v / (1.0f + __expf(-v));
          outb[idx] = __float2bfloat16(__bfloat162float(gate[idx]) * sv);
        }
      }
    }
  }
}

// ---------------- 256^2 8-phase GEMM, read-ahead pipelined fragments ----------------
// 512 thr = 8 waves (2M x 4N); wave owns 128x64. BK=64, LDS 128 KiB 2-dbuf.
// KEY (r3): every ds_read is issued ONE PHASE BEFORE its consuming MFMA, so the
// lgkm wait before an MFMA only drains reads issued a full phase earlier (hidden
// under the previous MFMA cluster). Frag sets: aP=A0, aQ=A1, bP=B0, bQ=B1.
//   p0: read B1->bQ (for p1);            stage SA0',SB0'; BAR; MMA(Q00:aP,bP); vm(4); BAR
//   p1: read A1->aQ (for p2);            stage SB1';      BAR; MMA(Q01:aP,bQ);        BAR
//   p2:                                  stage SA1';      BAR; MMA(Q11:aQ,bQ); vm(4); BAR  <- publishes next A0',B0'
//   p3: read next A0'->aP (pre-MMA);                      BAR; MMA(Q10:aQ,bP);
//       read next B0'->bP (post-MMA, resolves WAR);              vm(2); BAR
// Wait ledger (stages/tile: p0:4, p1:2, p2:2; vmcnt covers wave-own loads only,
// barrier after each wait publishes cross-wave):
//   p0-end vm(4): outstanding = curA1(2)+4 new = 6 -> waits cur A1 (read at p1)
//   p2-end vm(4): outstanding = 8 -> waits next A0+B0 (read at p3)
//   p3-end vm(2): outstanding = nextB1(2)+nextA1(2) -> waits next B1 (read at p0')
// Steady-state outstanding in [2,8]; never drained to 0. Last tile: vm(0) at p0-end.
#define G256_BAR()  asm volatile("s_barrier" ::: "memory")
#define G256_VMW(N) asm volatile("s_waitcnt vmcnt(" #N ")" ::: "memory")

#define G256_DSA_INTO(dst, mh_, SRC) \
  { _Pragma("unroll") for (int mt = 0; mt < 4; ++mt) { \
      const int rb_ = (rbA + (mh_) * 64 + mt * 16) * 64; \
      dst[mt][0] = *(const bf16_8*)&SRC[rb_ + p0]; \
      dst[mt][1] = *(const bf16_8*)&SRC[rb_ + p1]; } }

#define G256_DSB_INTO(dst, nh_, SRC) \
  { _Pragma("unroll") for (int nt = 0; nt < 2; ++nt) { \
      const int rb_ = (rbB + (nh_) * 32 + nt * 16) * 64; \
      dst[nt][0] = *(const bf16_8*)&SRC[rb_ + p0]; \
      dst[nt][1] = *(const bf16_8*)&SRC[rb_ + p1]; } }

#define G256_MMA(aset, bset, mh_, nh_) \
  { __builtin_amdgcn_s_setprio(1); \
    _Pragma("unroll") for (int kk = 0; kk < 2; ++kk) \
      _Pragma("unroll") for (int mt = 0; mt < 4; ++mt) \
        _Pragma("unroll") for (int nt = 0; nt < 2; ++nt) \
          acc[(mh_) * 4 + mt][(nh_) * 2 + nt] = __builtin_amdgcn_mfma_f32_16x16x32_bf16( \
              aset[mt][kk], bset[nt][kk], acc[(mh_) * 4 + mt][(nh_) * 2 + nt], 0, 0, 0); \
    __builtin_amdgcn_s_setprio(0); }

#define G256_TILE(CUR, kt_) { \
    const __hip_bfloat16* Ac = As[CUR]; \
    const __hip_bfloat16* Bc = Bs[CUR]; \
    const __hip_bfloat16* An = As[(CUR) ^ 1]; \
    const __hip_bfloat16* Bn = Bs[(CUR) ^ 1]; \
    const int nb_ = (CUR) ^ 1; \
    const bool pf = ((kt_) + 1) < NT; \
    const int kn = ((kt_) + 1) << 6; \
    /* p0 */ \
    G256_DSB_INTO(bQ, 1, Bc); \
    if (pf) { stageA(0, nb_, kn); stageB(0, nb_, kn); } \
    G256_BAR(); G256_MMA(aP, bP, 0, 0); \
    if (pf) { G256_VMW(4); } else { G256_VMW(0); } \
    G256_BAR(); \
    /* p1 */ \
    G256_DSA_INTO(aQ, 1, Ac); \
    if (pf) { stageB(1, nb_, kn); } \
    G256_BAR(); G256_MMA(aP, bQ, 0, 1); \
    G256_BAR(); \
    /* p2 */ \
    if (pf) { stageA(1, nb_, kn); } \
    G256_BAR(); G256_MMA(aQ, bQ, 1, 1); \
    if (pf) { G256_VMW(4); } \
    G256_BAR(); \
    /* p3 */ \
    if (pf) { G256_DSA_INTO(aP, 0, An); } \
    G256_BAR(); G256_MMA(aQ, bP, 1, 0); \
    if (pf) { G256_DSB_INTO(bP, 0, Bn); G256_VMW(2); } \
    G256_BAR(); \
  }

template <int EPI>
__global__ __launch_bounds__(512, 2) void gemm256(
    const __hip_bfloat16* __restrict__ A,
    const __hip_bfloat16* __restrict__ Bw,
    const float* __restrict__ resid,
    const __hip_bfloat16* __restrict__ gate,
    __hip_bfloat16* __restrict__ outb,
    float* __restrict__ outf,
    int N, int K) {
  __shared__ __hip_bfloat16 As[2][256 * 64];   // 64 KiB
  __shared__ __hip_bfloat16 Bs[2][256 * 64];   // 64 KiB
  const int t = threadIdx.x;
  const int w = t >> 6, lane = t & 63;
  const int wm = w >> 2, wn = w & 3;           // 2M x 4N wave grid
  const int quad = lane >> 4, l16 = lane & 15;

  // bijective XCD swizzle (nwg % 8 == 0 for all call sites)
  const int gx = gridDim.x;
  const int nwg = gx * gridDim.y;
  int lin = blockIdx.y * gx + blockIdx.x;
  lin = (lin & 7) * (nwg >> 3) + (lin >> 3);
  const int m0 = (lin / gx) * 256;
  const int n0 = (lin % gx) * 256;

  const __hip_bfloat16* Ab = A + (size_t)m0 * K;
  const __hip_bfloat16* Bb = Bw + (size_t)n0 * K;

  // staging: per half-tile each wave issues 2x global_load_lds (1 KiB each,
  // 8 rows x 128 B); source chunk pre-swizzled so linear LDS + swizzled read.
  const int rl = lane >> 3;                    // row within 8-row group
  const int c0 = (((lane & 7) ^ rl) << 3);     // swizzled source chunk (elems)

  auto stageA = [&](int h, int buf, int k0) {
    const int r0 = h * 64 + (w << 3);          // rows [h*64+w*8, +8)
    async16(Ab + (size_t)(r0 + rl) * K + k0 + c0, &As[buf][r0 * 64]);
    const int r1 = r0 + 128;                   // rows [128+h*64+w*8, +8)
    async16(Ab + (size_t)(r1 + rl) * K + k0 + c0, &As[buf][r1 * 64]);
  };
  auto stageB = [&](int h, int buf, int k0) {
    const int s0 = (w >> 2) * 64 + h * 32 + (w & 3) * 8;
    async16(Bb + (size_t)(s0 + rl) * K + k0 + c0, &Bs[buf][s0 * 64]);
    const int s1 = s0 + 128;
    async16(Bb + (size_t)(s1 + rl) * K + k0 + c0, &Bs[buf][s1 * 64]);
  };

  // fragment read bases: row = rbA + mh*64 + mt*16 ; pos = (q ^ (l16&7))*8
  const int rbA = wm * 128 + l16;
  const int rbB = wn * 64 + l16;
  const int p0 = ((quad ^ (l16 & 7)) << 3);
  const int p1 = (((4 + quad) ^ (l16 & 7)) << 3);

  f32x4 acc[8][4] = {};
  bf16_8 aP[4][2], aQ[4][2], bP[2][2], bQ[2][2];
  const int NT = K >> 6;                       // even (K = 1024 or 4096)

  // prologue: tile 0 -> buf 0 (8 loads). vm(4)+BAR publishes A0,B0; read them
  // ahead into aP/bP; vm(2)+BAR publishes B1 (read at tile0.p0).
  stageA(0, 0, 0); stageB(0, 0, 0); stageB(1, 0, 0); stageA(1, 0, 0);
  G256_VMW(4); G256_BAR();
  G256_DSA_INTO(aP, 0, As[0]); G256_DSB_INTO(bP, 0, Bs[0]);
  G256_VMW(2); G256_BAR();

  for (int kt = 0; kt < NT; kt += 2) {
    G256_TILE(0, kt);
    G256_TILE(1, kt + 1);
  }

  #pragma unroll
  for (int mf = 0; mf < 8; ++mf) {
    #pragma unroll
    for (int nf = 0; nf < 4; ++nf) {
      #pragma unroll
      for (int r = 0; r < 4; ++r) {
        const int row = m0 + wm * 128 + mf * 16 + quad * 4 + r;
        const int col = n0 + wn * 64 + nf * 16 + l16;
        const size_t idx = (size_t)row * N + col;
        const float v = acc[mf][nf][r];
        if (EPI == EPI_BF16) {
          outb[idx] = __float2bfloat16(v);
        } else if (EPI == EPI_RESID) {
          outf[idx] = resid[idx] + v;
        } else {
          const float sv = v / (1.0f + __expf(-v));
          outb[idx] = __float2bfloat16(__bfloat162float(gate[idx]) * sv);
        }
      }
    }
  }
}

// ---------------- sliding-window flash attention ----------------
__global__ __launch_bounds__(256) void attn_k(const __hip_bfloat16* __restrict__ qr,
                                              const __hip_bfloat16* __restrict__ kr,
                                              const __hip_bfloat16* __restrict__ Vt,
                                              __hip_bfloat16* __restrict__ y,
                                              const int* __restrict__ winp) {
  __shared__ __hip_bfloat16 Ksm[64 * 128];   // key-major, swizzled
  __shared__ __hip_bfloat16 Vsm[128 * 64];   // dim-major, swizzled
  __shared__ __hip_bfloat16 Psm[4 * 16 * 72];
  const int t = threadIdx.x, w = t >> 6, lane = t & 63;
  const int quad = lane >> 4, l16 = lane & 15;
  const int b = blockIdx.y, t0 = blockIdx.x * 64;
  const int tw0 = t0 + w * 16;
  const int win = *winp;
  int kb_lo = t0 - win;
  if (kb_lo < 0) kb_lo = 0;
  kb_lo &= ~63;

  bf16_8 qf[4];
  const __hip_bfloat16* qb = qr + ((size_t)(b * TT + tw0 + l16)) * 128 + quad * 8;
  #pragma unroll
  for (int kk = 0; kk < 4; ++kk) qf[kk] = *(const bf16_8*)(qb + kk * 32);

  f32x4 o[8] = {};
  float mrow[4] = {-1e30f, -1e30f, -1e30f, -1e30f};
  float lrow[4] = {0.f, 0.f, 0.f, 0.f};
  const float scale = 0.08838834764831845f;  // 1/sqrt(128)

  const int krow_loc = (w * 4) + (lane >> 4);
  const int kc = ((lane & 15) ^ (krow_loc & 15)) << 3;
  const int vloc = lane >> 3;
  const int vc = ((lane & 7) ^ vloc) << 3;

  for (int kb0 = kb_lo; kb0 <= t0; kb0 += 64) {
    const __hip_bfloat16* kbp = kr + ((size_t)(b * TT + kb0)) * 128;
    #pragma unroll
    for (int i = 0; i < 4; ++i) {
      const int krow = i * 16 + krow_loc;
      async16(kbp + (size_t)krow * 128 + kc, &Ksm[i * 2048 + w * 512]);
    }
    #pragma unroll
    for (int i = 0; i < 4; ++i) {
      const int d0 = (i * 4 + w) * 8;
      const int dr = d0 + vloc;
      async16(Vt + ((size_t)(b * 128 + dr)) * TT + kb0 + vc, &Vsm[d0 * 64]);
    }
    __syncthreads();

    f32x4 s[4] = {};
    #pragma unroll
    for (int kk = 0; kk < 4; ++kk) {
      #pragma unroll
      for (int nt = 0; nt < 4; ++nt) {
        const int cc = ((kk * 4 + quad) ^ l16) << 3;
        const bf16_8 bfrag = *(const bf16_8*)&Ksm[(nt * 16 + l16) * 128 + cc];
        s[nt] = __builtin_amdgcn_mfma_f32_16x16x32_bf16(qf[kk], bfrag, s[nt], 0, 0, 0);
      }
    }

    float mb[4] = {-1e30f, -1e30f, -1e30f, -1e30f};
    #pragma unroll
    for (int nt = 0; nt < 4; ++nt) {
      #pragma unroll
      for (int r = 0; r < 4; ++r) {
        const int tq = tw0 + quad * 4 + r;
        const int scol = kb0 + nt * 16 + l16;
        float v = s[nt][r] * scale;
        const bool ok = (scol <= tq) && (tq - scol <= win);
        v = ok ? v : -1e30f;
        s[nt][r] = v;
        mb[r] = fmaxf(mb[r], v);
      }
    }

    #pragma unroll
    for (int r = 0; r < 4; ++r) {
      float m = mb[r];
      m = fmaxf(m, __shfl_xor(m, 1, 16));
      m = fmaxf(m, __shfl_xor(m, 2, 16));
      m = fmaxf(m, __shfl_xor(m, 4, 16));
      m = fmaxf(m, __shfl_xor(m, 8, 16));
      const float mn = fmaxf(mrow[r], m);
      const float alpha = __expf(mrow[r] - mn);
      mrow[r] = mn;
      float rs = 0.f;
      #pragma unroll
      for (int nt = 0; nt < 4; ++nt) {
        const float pv = __expf(s[nt][r] - mn);
        s[nt][r] = pv;
        rs += pv;
      }
      rs += __shfl_xor(rs, 1, 16);
      rs += __shfl_xor(rs, 2, 16);
      rs += __shfl_xor(rs, 4, 16);
      rs += __shfl_xor(rs, 8, 16);
      lrow[r] = lrow[r] * alpha + rs;
      #pragma unroll
      for (int n2 = 0; n2 < 8; ++n2) o[n2][r] *= alpha;
    }

    __hip_bfloat16* pw = &Psm[w * 1152];
    #pragma unroll
    for (int nt = 0; nt < 4; ++nt) {
      #pragma unroll
      for (int r = 0; r < 4; ++r)
        pw[(quad * 4 + r) * 72 + nt * 16 + l16] = __float2bfloat16(s[nt][r]);
    }
    asm volatile("s_waitcnt lgkmcnt(0)" ::: "memory");

    #pragma unroll
    for (int kk2 = 0; kk2 < 2; ++kk2) {
      const bf16_8 pa = *(const bf16_8*)&Psm[w * 1152 + l16 * 72 + kk2 * 32 + quad * 8];
      #pragma unroll
      for (int n2 = 0; n2 < 8; ++n2) {
        const int cc = ((kk2 * 4 + quad) ^ (l16 & 7)) << 3;
        const bf16_8 vb = *(const bf16_8*)&Vsm[(n2 * 16 + l16) * 64 + cc];
        o[n2] = __builtin_amdgcn_mfma_f32_16x16x32_bf16(pa, vb, o[n2], 0, 0, 0);
      }
    }
    __syncthreads();
  }

  #pragma unroll
  for (int n2 = 0; n2 < 8; ++n2) {
    #pragma unroll
    for (int r = 0; r < 4; ++r) {
      const int row = b * TT + tw0 + quad * 4 + r;
      const int col = n2 * 16 + l16;
      y[(size_t)row * 128 + col] = __float2bfloat16(o[n2][r] / lrow[r]);
    }
  }
}

// ---------------- launch ----------------
extern "C" void kernel_launch(void* const* d_in, const int* in_sizes, int n_in,
                              void* d_out, int out_size, void* d_ws, size_t ws_size,
                              hipStream_t stream) {
  const float* x    = (const float*)d_in[0];
  const float* Uq   = (const float*)d_in[1];
  const float* Uk   = (const float*)d_in[2];
  const float* Uv   = (const float*)d_in[3];
  const float* cosb = (const float*)d_in[4];
  const float* sinb = (const float*)d_in[5];
  const float* ln1  = (const float*)d_in[6];
  const float* ln2  = (const float*)d_in[7];
  const float* Wo   = (const float*)d_in[8];
  const float* w1   = (const float*)d_in[9];
  const float* w3   = (const float*)d_in[10];
  const float* w2   = (const float*)d_in[11];
  const int*   winp = (const int*)d_in[12];
  float* out = (float*)d_out;

  uint8_t* p = (uint8_t*)d_ws;
  auto take = [&](size_t bytes) {
    uint8_t* q = p;
    p += (bytes + 255) & ~(size_t)255;
    return q;
  };

  __hip_bfloat16* h1     = (__hip_bfloat16*)take((size_t)BT * DFFC * 2);  // 128 MB
  __hip_bfloat16* gb     = h1;       // aliased: gate epilogue same-idx read->write
  __hip_bfloat16* normed = (__hip_bfloat16*)take((size_t)BT * DD * 2);    // 32 MB
  __hip_bfloat16* hb     = normed;   // aliased: normed dead after qkv gemm
  __hip_bfloat16* qkv    = (__hip_bfloat16*)take((size_t)BT * 384 * 2);   // 12 MB
  __hip_bfloat16* yb     = qkv;      // aliased: qkv dead after rope+vtrans
  __hip_bfloat16* qr_    = (__hip_bfloat16*)take((size_t)BT * RR * 2);    // 4 MB
  __hip_bfloat16* kr_    = (__hip_bfloat16*)take((size_t)BT * RR * 2);    // 4 MB
  __hip_bfloat16* Vt     = (__hip_bfloat16*)take((size_t)BT * RR * 2);    // 4 MB
  __hip_bfloat16* Ucat   = (__hip_bfloat16*)take((size_t)384 * DD * 2);
  __hip_bfloat16* Wob    = (__hip_bfloat16*)take((size_t)DD * RR * 2);
  __hip_bfloat16* W1b    = (__hip_bfloat16*)take((size_t)DFFC * DD * 2);
  __hip_bfloat16* W3b    = (__hip_bfloat16*)take((size_t)DFFC * DD * 2);
  __hip_bfloat16* W2b    = (__hip_bfloat16*)take((size_t)DD * DFFC * 2);
  float* x_mid = out;  // x_mid lives in d_out (fp32); resid alias is data-dep safe

  // weight converts
  cvt_k<<<128, 256, 0, stream>>>(Uq, Ucat, RR * DD / 4);
  cvt_k<<<128, 256, 0, stream>>>(Uk, Ucat + (size_t)RR * DD, RR * DD / 4);
  cvt_k<<<128, 256, 0, stream>>>(Uv, Ucat + (size_t)2 * RR * DD, RR * DD / 4);
  cvt_k<<<128, 256, 0, stream>>>(Wo, Wob, DD * RR / 4);
  cvt_k<<<4096, 256, 0, stream>>>(w1, W1b, DFFC * DD / 4);
  cvt_k<<<4096, 256, 0, stream>>>(w3, W3b, DFFC * DD / 4);
  cvt_k<<<4096, 256, 0, stream>>>(w2, W2b, DD * DFFC / 4);

  // rmsnorm1
  rmsnorm_k<<<BT, 256, 0, stream>>>(x, ln1, normed);

  // qkv = normed @ Ucat^T   (M=16384, N=384, K=1024)  -- 128^2 kernel (N%256!=0)
  gemm_bt<EPI_BF16><<<dim3(3, 128), 256, 0, stream>>>(normed, Ucat, nullptr, nullptr,
                                                      qkv, nullptr, 384, DD);

  // rope q,k ; transpose v
  rope_k<<<BT * 64 / 256, 256, 0, stream>>>(qkv, cosb, sinb, qr_, kr_);
  vtrans_k<<<dim3(TT / 64, NB), 256, 0, stream>>>(qkv, Vt);

  // attention (writes yb over the dead qkv region)
  attn_k<<<dim3(TT / 64, NB), 256, 0, stream>>>(qr_, kr_, Vt, yb, winp);

  // x_mid = x + y @ Wo^T   (N=1024, K=128)  -> d_out   -- 128^2 kernel (K too short)
  gemm_bt<EPI_RESID><<<dim3(8, 128), 256, 0, stream>>>(yb, Wob, x, nullptr,
                                                       nullptr, x_mid, DD, RR);

  // rmsnorm2 (reads d_out, writes hb over dead normed)
  rmsnorm_k<<<BT, 256, 0, stream>>>(x_mid, ln2, hb);

  // h1 = h @ w1^T           (M=16384, N=4096, K=1024)  -- 8-phase 256^2
  gemm256<EPI_BF16><<<dim3(16, 64), 512, 0, stream>>>(hb, W1b, nullptr, nullptr,
                                                      h1, nullptr, DFFC, DD);
  // g = h1 * silu(h @ w3^T)
  gemm256<EPI_GATE><<<dim3(16, 64), 512, 0, stream>>>(hb, W3b, nullptr, h1,
                                                      gb, nullptr, DFFC, DD);
  // out = x_mid + g @ w2^T  (N=1024, K=4096)
  gemm256<EPI_RESID><<<dim3(4, 64), 512, 0, stream>>>(gb, W2b, x_mid, nullptr,
                                                      nullptr, out, DD, DFFC);
}

// Round 5
// 736.776 us; speedup vs baseline: 1.7921x; 1.7921x over previous
//
#include <hip/hip_runtime.h>
#include <hip/hip_bf16.h>
#include <stdint.h>

#define BT   16384   // B*T
#define TT   4096    // T
#define NB   4       // B
#define DD   1024
#define RR   128
#define DFFC 4096

typedef __bf16 bf16_8 __attribute__((ext_vector_type(8)));
typedef float  f32x4  __attribute__((ext_vector_type(4)));

__device__ __forceinline__ void async16(const void* g, void* l) {
  __builtin_amdgcn_global_load_lds((__attribute__((address_space(1))) void*)(g),
                                   (__attribute__((address_space(3))) void*)(l),
                                   16, 0, 0);
}

// ---------------- fp32 -> bf16 convert ----------------
__global__ __launch_bounds__(256) void cvt_k(const float* __restrict__ src,
                                             __hip_bfloat16* __restrict__ dst, int n4) {
  const int i = blockIdx.x * 256 + threadIdx.x;
  if (i >= n4) return;
  const float4 v = ((const float4*)src)[i];
  __hip_bfloat16* o = dst + (size_t)i * 4;
  o[0] = __float2bfloat16(v.x);
  o[1] = __float2bfloat16(v.y);
  o[2] = __float2bfloat16(v.z);
  o[3] = __float2bfloat16(v.w);
}

// ---------------- RMSNorm (fp32 in, bf16 out) ----------------
__global__ __launch_bounds__(256) void rmsnorm_k(const float* __restrict__ x,
                                                 const float* __restrict__ wgt,
                                                 __hip_bfloat16* __restrict__ out) {
  const int row = blockIdx.x;
  const int t = threadIdx.x;
  const float4 v = ((const float4*)(x + (size_t)row * DD))[t];
  float ss = v.x*v.x + v.y*v.y + v.z*v.z + v.w*v.w;
  #pragma unroll
  for (int m = 1; m < 64; m <<= 1) ss += __shfl_xor(ss, m, 64);
  __shared__ float red[4];
  if ((t & 63) == 0) red[t >> 6] = ss;
  __syncthreads();
  ss = red[0] + red[1] + red[2] + red[3];
  const float rms = rsqrtf(ss * (1.0f / DD) + 1e-6f);
  const float4 wv = ((const float4*)wgt)[t];
  __hip_bfloat16* o = out + (size_t)row * DD + t * 4;
  o[0] = __float2bfloat16(v.x * rms * wv.x);
  o[1] = __float2bfloat16(v.y * rms * wv.y);
  o[2] = __float2bfloat16(v.z * rms * wv.z);
  o[3] = __float2bfloat16(v.w * rms * wv.w);
}

// ---------------- RoPE: qkv (M,384) -> qr, kr (M,128) ----------------
__global__ __launch_bounds__(256) void rope_k(const __hip_bfloat16* __restrict__ qkv,
                                              const float* __restrict__ cosb,
                                              const float* __restrict__ sinb,
                                              __hip_bfloat16* __restrict__ qr,
                                              __hip_bfloat16* __restrict__ kr) {
  const int idx = blockIdx.x * 256 + threadIdx.x;  // 0 .. BT*64-1
  const int row = idx >> 6;
  const int i = idx & 63;
  const int tpos = row & (TT - 1);
  const float c = cosb[tpos * 64 + i];
  const float s = sinb[tpos * 64 + i];
  const size_t base = (size_t)row * 384;
  const float q1 = __bfloat162float(qkv[base + i]);
  const float q2 = __bfloat162float(qkv[base + 64 + i]);
  const float k1 = __bfloat162float(qkv[base + 128 + i]);
  const float k2 = __bfloat162float(qkv[base + 192 + i]);
  const size_t ob = (size_t)row * 128;
  qr[ob + i]      = __float2bfloat16( q1 * c + q2 * s);
  qr[ob + 64 + i] = __float2bfloat16(-q1 * s + q2 * c);
  kr[ob + i]      = __float2bfloat16( k1 * c + k2 * s);
  kr[ob + 64 + i] = __float2bfloat16(-k1 * s + k2 * c);
}

// ---------------- V transpose: qkv v-cols -> Vt (B,128,T) ----------------
__global__ __launch_bounds__(256) void vtrans_k(const __hip_bfloat16* __restrict__ qkv,
                                                __hip_bfloat16* __restrict__ Vt) {
  const int b = blockIdx.y, t0 = blockIdx.x * 64, t = threadIdx.x;
  #pragma unroll
  for (int i = 0; i < 4; ++i) {
    const int flat8 = i * 256 + t;       // 0..1023
    const int row = flat8 >> 4;          // 0..63  (t-local)
    const int d8 = (flat8 & 15) * 8;     // dim start
    const bf16_8 v = *(const bf16_8*)&qkv[((size_t)(b * TT + t0 + row)) * 384 + 256 + d8];
    #pragma unroll
    for (int j = 0; j < 8; ++j)
      ((__bf16*)Vt)[((size_t)(b * 128 + d8 + j)) * TT + t0 + row] = v[j];
  }
}

// ---------------- GEMM: C(M,N) = A(M,K) @ Bw(N,K)^T, bf16 MFMA ----------------
// 128^2 tile, 2-barrier loop. Kept for qkv (N=384) and Wo (K=128).
enum { EPI_BF16 = 0, EPI_RESID = 1, EPI_GATE = 2 };

template <int EPI>
__global__ __launch_bounds__(256) void gemm_bt(
    const __hip_bfloat16* __restrict__ A,
    const __hip_bfloat16* __restrict__ Bw,
    const float* __restrict__ resid,
    const __hip_bfloat16* __restrict__ gate,
    __hip_bfloat16* __restrict__ outb,
    float* __restrict__ outf,
    int N, int K) {
  __shared__ __hip_bfloat16 As[128 * 64];
  __shared__ __hip_bfloat16 Bs[128 * 64];
  const int t = threadIdx.x;
  const int w = t >> 6, lane = t & 63;
  const int wm = w >> 1, wn = w & 1;
  const int quad = lane >> 4, l16 = lane & 15;
  const int m0 = blockIdx.y * 128, n0 = blockIdx.x * 128;

  const __hip_bfloat16* Ab = A + (size_t)m0 * K;
  const __hip_bfloat16* Bb = Bw + (size_t)n0 * K;

  const int rloc = w * 8 + (lane >> 3);
  const int c0 = (((lane & 7) ^ ((lane >> 3) & 7)) << 3);
  const int swz = (l16 & 7);

  f32x4 acc[4][4] = {};

  for (int k0 = 0; k0 < K; k0 += 64) {
    #pragma unroll
    for (int j = 0; j < 4; ++j) {
      async16(Ab + (size_t)(j * 32 + rloc) * K + k0 + c0, &As[j * 2048 + w * 512]);
      async16(Bb + (size_t)(j * 32 + rloc) * K + k0 + c0, &Bs[j * 2048 + w * 512]);
    }
    __syncthreads();
    #pragma unroll
    for (int kc = 0; kc < 2; ++kc) {
      bf16_8 af[4], bfr[4];
      #pragma unroll
      for (int i = 0; i < 4; ++i) {
        const int pos = (((kc * 4 + quad) ^ swz) << 3);
        af[i]  = *(const bf16_8*)&As[(wm * 64 + i * 16 + l16) * 64 + pos];
        bfr[i] = *(const bf16_8*)&Bs[(wn * 64 + i * 16 + l16) * 64 + pos];
      }
      #pragma unroll
      for (int mt = 0; mt < 4; ++mt) {
        #pragma unroll
        for (int nt = 0; nt < 4; ++nt)
          acc[mt][nt] = __builtin_amdgcn_mfma_f32_16x16x32_bf16(af[mt], bfr[nt], acc[mt][nt], 0, 0, 0);
      }
    }
    __syncthreads();
  }

  #pragma unroll
  for (int mt = 0; mt < 4; ++mt) {
    #pragma unroll
    for (int nt = 0; nt < 4; ++nt) {
      #pragma unroll
      for (int r = 0; r < 4; ++r) {
        const int row = m0 + wm * 64 + mt * 16 + quad * 4 + r;
        const int col = n0 + wn * 64 + nt * 16 + l16;
        const size_t idx = (size_t)row * N + col;
        const float v = acc[mt][nt][r];
        if (EPI == EPI_BF16) {
          outb[idx] = __float2bfloat16(v);
        } else if (EPI == EPI_RESID) {
          outf[idx] = resid[idx] + v;
        } else {
          const float sv = v / (1.0f + __expf(-v));
          outb[idx] = __float2bfloat16(__bfloat162float(gate[idx]) * sv);
        }
      }
    }
  }
}

// ---------------- 256^2 8-phase GEMM (r1 schedule, register-budget-safe) ----------------
// 512 thr = 8 waves (2M x 4N); wave owns 128x64 out. BK=64, LDS 128 KiB 2-dbuf.
// acc = 128 AGPR => arch-VGPR cap is 128 at 2 waves/SIMD (r3 lesson: exceeding
// it spills to scratch, 2x slowdown). This schedule keeps ~120 live: frags are
// re-read per phase, never pipelined across phases.
#define G256_BAR()  asm volatile("s_barrier" ::: "memory")
#define G256_VMW4() asm volatile("s_waitcnt vmcnt(4)" ::: "memory")
#define G256_VMW0() asm volatile("s_waitcnt vmcnt(0)" ::: "memory")

#define G256_DSA(mh_) \
  { _Pragma("unroll") for (int mt = 0; mt < 4; ++mt) { \
      const int rb_ = (rbA + (mh_) * 64 + mt * 16) * 64; \
      a[mt][0] = *(const bf16_8*)&Ac[rb_ + p0]; \
      a[mt][1] = *(const bf16_8*)&Ac[rb_ + p1]; } }

#define G256_DSB(nh_) \
  { _Pragma("unroll") for (int nt = 0; nt < 2; ++nt) { \
      const int rb_ = (rbB + (nh_) * 32 + nt * 16) * 64; \
      b[nt][0] = *(const bf16_8*)&Bc[rb_ + p0]; \
      b[nt][1] = *(const bf16_8*)&Bc[rb_ + p1]; } }

#define G256_MMA(mh_, nh_) \
  { __builtin_amdgcn_s_setprio(1); \
    _Pragma("unroll") for (int kk = 0; kk < 2; ++kk) \
      _Pragma("unroll") for (int mt = 0; mt < 4; ++mt) \
        _Pragma("unroll") for (int nt = 0; nt < 2; ++nt) \
          acc[(mh_) * 4 + mt][(nh_) * 2 + nt] = __builtin_amdgcn_mfma_f32_16x16x32_bf16( \
              a[mt][kk], b[nt][kk], acc[(mh_) * 4 + mt][(nh_) * 2 + nt], 0, 0, 0); \
    __builtin_amdgcn_s_setprio(0); }

#define G256_TILE(CUR, kt_) { \
    const __hip_bfloat16* Ac = As[CUR]; \
    const __hip_bfloat16* Bc = Bs[CUR]; \
    const int nb_ = (CUR) ^ 1; \
    const bool pf = ((kt_) + 1) < NT; \
    const int kn = ((kt_) + 1) << 6; \
    if (!pf) { G256_VMW0(); G256_BAR(); } \
    G256_DSA(0); G256_DSB(0); if (pf) { stageA(0, nb_, kn); } \
    G256_BAR(); G256_MMA(0, 0); G256_VMW4(); G256_BAR(); \
    G256_DSB(1); if (pf) { stageB(0, nb_, kn); } \
    G256_BAR(); G256_MMA(0, 1); G256_VMW4(); G256_BAR(); \
    G256_DSA(1); if (pf) { stageB(1, nb_, kn); } \
    G256_BAR(); G256_MMA(1, 1); G256_VMW4(); G256_BAR(); \
    G256_DSB(0); if (pf) { stageA(1, nb_, kn); } \
    G256_BAR(); G256_MMA(1, 0); G256_VMW4(); G256_BAR(); \
  }

template <int EPI>
__global__ __launch_bounds__(512, 2) void gemm256(
    const __hip_bfloat16* __restrict__ A,
    const __hip_bfloat16* __restrict__ Bw,
    const float* __restrict__ resid,
    const __hip_bfloat16* __restrict__ gate,
    __hip_bfloat16* __restrict__ outb,
    float* __restrict__ outf,
    int N, int K) {
  __shared__ __hip_bfloat16 As[2][256 * 64];   // 64 KiB
  __shared__ __hip_bfloat16 Bs[2][256 * 64];   // 64 KiB
  const int t = threadIdx.x;
  const int w = t >> 6, lane = t & 63;
  const int wm = w >> 2, wn = w & 3;           // 2M x 4N wave grid
  const int quad = lane >> 4, l16 = lane & 15;

  // bijective XCD swizzle (nwg % 8 == 0 for all call sites)
  const int gx = gridDim.x;
  const int nwg = gx * gridDim.y;
  int lin = blockIdx.y * gx + blockIdx.x;
  lin = (lin & 7) * (nwg >> 3) + (lin >> 3);
  const int m0 = (lin / gx) * 256;
  const int n0 = (lin % gx) * 256;

  const __hip_bfloat16* Ab = A + (size_t)m0 * K;
  const __hip_bfloat16* Bb = Bw + (size_t)n0 * K;

  const int rl = lane >> 3;                    // row within 8-row group
  const int c0 = (((lane & 7) ^ rl) << 3);     // swizzled source chunk (elems)

  auto stageA = [&](int h, int buf, int k0) {
    const int r0 = h * 64 + (w << 3);
    async16(Ab + (size_t)(r0 + rl) * K + k0 + c0, &As[buf][r0 * 64]);
    const int r1 = r0 + 128;
    async16(Ab + (size_t)(r1 + rl) * K + k0 + c0, &As[buf][r1 * 64]);
  };
  auto stageB = [&](int h, int buf, int k0) {
    const int s0 = (w >> 2) * 64 + h * 32 + (w & 3) * 8;
    async16(Bb + (size_t)(s0 + rl) * K + k0 + c0, &Bs[buf][s0 * 64]);
    const int s1 = s0 + 128;
    async16(Bb + (size_t)(s1 + rl) * K + k0 + c0, &Bs[buf][s1 * 64]);
  };

  const int rbA = wm * 128 + l16;
  const int rbB = wn * 64 + l16;
  const int p0 = ((quad ^ (l16 & 7)) << 3);
  const int p1 = (((4 + quad) ^ (l16 & 7)) << 3);

  f32x4 acc[8][4] = {};
  bf16_8 a[4][2], b[2][2];
  const int NT = K >> 6;                       // even (K = 1024 or 4096)

  stageA(0, 0, 0); stageB(0, 0, 0); stageB(1, 0, 0); stageA(1, 0, 0);
  G256_VMW4(); G256_BAR();

  for (int kt = 0; kt < NT; kt += 2) {
    G256_TILE(0, kt);
    G256_TILE(1, kt + 1);
  }

  #pragma unroll
  for (int mf = 0; mf < 8; ++mf) {
    #pragma unroll
    for (int nf = 0; nf < 4; ++nf) {
      #pragma unroll
      for (int r = 0; r < 4; ++r) {
        const int row = m0 + wm * 128 + mf * 16 + quad * 4 + r;
        const int col = n0 + wn * 64 + nf * 16 + l16;
        const size_t idx = (size_t)row * N + col;
        const float v = acc[mf][nf][r];
        if (EPI == EPI_BF16) {
          outb[idx] = __float2bfloat16(v);
        } else if (EPI == EPI_RESID) {
          outf[idx] = resid[idx] + v;
        } else {
          const float sv = v / (1.0f + __expf(-v));
          outb[idx] = __float2bfloat16(__bfloat162float(gate[idx]) * sv);
        }
      }
    }
  }
}

// ---------------- fused FFN up+gate: gb = (h@w1^T) * silu(h@w3^T) ----------------
// Tile 256m x 128n; 8 waves 4M x 2N; wave owns 64x64 per matrix. BK=64.
// LDS: A 256x64 dbuf (64K) + B1 128x64 dbuf (32K) + B3 dbuf (32K) = 128 KiB.
// A staged ONCE serves both matrices; gate fused in-register (no h1 round-trip).
// Registers: acc1+acc3 = 128 AGPR; A frags 32 + B frags 16 VGPR -> fits 128 cap.
// Phases: p0 MMA1-nh0, p1 MMA1-nh1, p2 MMA3-nh0, p3 MMA3-nh1.
// ds_reads: p0: A(8)+B1nh0(4)=12; p1: B1nh1(4); p2: B3nh0(4); p3: B3nh1(4).
// Stage (next buf): p0: A-h0'(2)+B1'(2); p1: A-h1'(2); p2: B3'(2); p3: none.
// Wait ledger (outstanding oldest->newest; invariant at tile start = [B3_t(2)]):
//   p1-end vm(6): queue [B3_t(2), Ah0'B1'(4), Ah1'(2)]=8 -> publishes B3_t
//                 (read p2; staged prev-p2 = 3-phase margin)
//   p3-end vm(2): queue [Ah0'B1'(4), Ah1'(2), B3'(2)]=8 -> publishes A'+B1'
//                 (read next-p0; margins 3/2 phases); leaves [B3'(2)] = invariant
// Last tile: no stages; p1-end vm(0) drains B3_last.
#define F13_DSA() \
  { _Pragma("unroll") for (int mt = 0; mt < 4; ++mt) { \
      const int rb_ = (rbA + mt * 16) * 64; \
      a[mt][0] = *(const bf16_8*)&Ac[rb_ + p0]; \
      a[mt][1] = *(const bf16_8*)&Ac[rb_ + p1]; } }

#define F13_DSB(nh_, SRC) \
  { _Pragma("unroll") for (int nt = 0; nt < 2; ++nt) { \
      const int rb_ = (rbB + (nh_) * 32 + nt * 16) * 64; \
      b[nt][0] = *(const bf16_8*)&SRC[rb_ + p0]; \
      b[nt][1] = *(const bf16_8*)&SRC[rb_ + p1]; } }

#define F13_MMA(ACC, nh_) \
  { __builtin_amdgcn_s_setprio(1); \
    _Pragma("unroll") for (int kk = 0; kk < 2; ++kk) \
      _Pragma("unroll") for (int mt = 0; mt < 4; ++mt) \
        _Pragma("unroll") for (int nt = 0; nt < 2; ++nt) \
          ACC[mt][(nh_) * 2 + nt] = __builtin_amdgcn_mfma_f32_16x16x32_bf16( \
              a[mt][kk], b[nt][kk], ACC[mt][(nh_) * 2 + nt], 0, 0, 0); \
    __builtin_amdgcn_s_setprio(0); }

#define F13_VMW(N) asm volatile("s_waitcnt vmcnt(" #N ")" ::: "memory")

#define F13_TILE(CUR, kt_) { \
    const __hip_bfloat16* Ac  = As[CUR]; \
    const __hip_bfloat16* B1c = B1s[CUR]; \
    const __hip_bfloat16* B3c = B3s[CUR]; \
    const int nb_ = (CUR) ^ 1; \
    const bool pf = ((kt_) + 1) < NT; \
    const int kn = ((kt_) + 1) << 6; \
    /* p0 */ \
    F13_DSA(); F13_DSB(0, B1c); \
    if (pf) { stageA2(0, nb_, kn); stageB1(nb_, kn); } \
    G256_BAR(); F13_MMA(acc1, 0); G256_BAR(); \
    /* p1 */ \
    F13_DSB(1, B1c); \
    if (pf) { stageA2(1, nb_, kn); } \
    G256_BAR(); F13_MMA(acc1, 1); \
    if (pf) { F13_VMW(6); } else { F13_VMW(0); } \
    G256_BAR(); \
    /* p2 */ \
    F13_DSB(0, B3c); \
    if (pf) { stageB3(nb_, kn); } \
    G256_BAR(); F13_MMA(acc3, 0); G256_BAR(); \
    /* p3 */ \
    F13_DSB(1, B3c); \
    G256_BAR(); F13_MMA(acc3, 1); \
    if (pf) { F13_VMW(2); } \
    G256_BAR(); \
  }

__global__ __launch_bounds__(512, 2) void gemm_ffn13(
    const __hip_bfloat16* __restrict__ A,     // hb (M,K)
    const __hip_bfloat16* __restrict__ B1w,   // w1 (N,K)
    const __hip_bfloat16* __restrict__ B3w,   // w3 (N,K)
    __hip_bfloat16* __restrict__ outb,        // gb (M,N)
    int N, int K) {
  __shared__ __hip_bfloat16 As[2][256 * 64];   // 64 KiB
  __shared__ __hip_bfloat16 B1s[2][128 * 64];  // 32 KiB
  __shared__ __hip_bfloat16 B3s[2][128 * 64];  // 32 KiB
  const int t = threadIdx.x;
  const int w = t >> 6, lane = t & 63;
  const int wm = w >> 1, wn = w & 1;           // 4M x 2N wave grid
  const int quad = lane >> 4, l16 = lane & 15;

  const int gx = gridDim.x;
  const int nwg = gx * gridDim.y;
  int lin = blockIdx.y * gx + blockIdx.x;
  lin = (lin & 7) * (nwg >> 3) + (lin >> 3);
  const int m0 = (lin / gx) * 256;
  const int n0 = (lin % gx) * 128;

  const __hip_bfloat16* Ab  = A   + (size_t)m0 * K;
  const __hip_bfloat16* B1b = B1w + (size_t)n0 * K;
  const __hip_bfloat16* B3b = B3w + (size_t)n0 * K;

  const int rl = lane >> 3;
  const int c0 = (((lane & 7) ^ rl) << 3);

  auto stageA2 = [&](int h, int buf, int k0) {   // A half h = 128 rows, 2 loads
    const int r0 = h * 128 + (w << 3);
    async16(Ab + (size_t)(r0 + rl) * K + k0 + c0, &As[buf][r0 * 64]);
    const int r1 = r0 + 64;
    async16(Ab + (size_t)(r1 + rl) * K + k0 + c0, &As[buf][r1 * 64]);
  };
  auto stageB1 = [&](int buf, int k0) {          // full 128 rows, 2 loads
    const int s0 = (w << 3);
    async16(B1b + (size_t)(s0 + rl) * K + k0 + c0, &B1s[buf][s0 * 64]);
    async16(B1b + (size_t)(s0 + 64 + rl) * K + k0 + c0, &B1s[buf][(s0 + 64) * 64]);
  };
  auto stageB3 = [&](int buf, int k0) {
    const int s0 = (w << 3);
    async16(B3b + (size_t)(s0 + rl) * K + k0 + c0, &B3s[buf][s0 * 64]);
    async16(B3b + (size_t)(s0 + 64 + rl) * K + k0 + c0, &B3s[buf][(s0 + 64) * 64]);
  };

  const int rbA = wm * 64 + l16;
  const int rbB = wn * 64 + l16;
  const int p0 = ((quad ^ (l16 & 7)) << 3);
  const int p1 = (((4 + quad) ^ (l16 & 7)) << 3);

  f32x4 acc1[4][4] = {};
  f32x4 acc3[4][4] = {};
  bf16_8 a[4][2], b[2][2];
  const int NT = K >> 6;                        // 16, even

  // prologue: queue order Ah0,B1,Ah1,B3 (8 loads); vm(2) publishes all but B3
  stageA2(0, 0, 0); stageB1(0, 0); stageA2(1, 0, 0); stageB3(0, 0);
  F13_VMW(2); G256_BAR();

  for (int kt = 0; kt < NT; kt += 2) {
    F13_TILE(0, kt);
    F13_TILE(1, kt + 1);
  }

  #pragma unroll
  for (int mt = 0; mt < 4; ++mt) {
    #pragma unroll
    for (int nt = 0; nt < 4; ++nt) {
      #pragma unroll
      for (int r = 0; r < 4; ++r) {
        const int row = m0 + wm * 64 + mt * 16 + quad * 4 + r;
        const int col = n0 + wn * 64 + nt * 16 + l16;
        const float g = acc3[mt][nt][r];
        const float sv = g / (1.0f + __expf(-g));
        outb[(size_t)row * N + col] = __float2bfloat16(acc1[mt][nt][r] * sv);
      }
    }
  }
}

// ---------------- sliding-window flash attention ----------------
__global__ __launch_bounds__(256) void attn_k(const __hip_bfloat16* __restrict__ qr,
                                              const __hip_bfloat16* __restrict__ kr,
                                              const __hip_bfloat16* __restrict__ Vt,
                                              __hip_bfloat16* __restrict__ y,
                                              const int* __restrict__ winp) {
  __shared__ __hip_bfloat16 Ksm[64 * 128];   // key-major, swizzled
  __shared__ __hip_bfloat16 Vsm[128 * 64];   // dim-major, swizzled
  __shared__ __hip_bfloat16 Psm[4 * 16 * 72];
  const int t = threadIdx.x, w = t >> 6, lane = t & 63;
  const int quad = lane >> 4, l16 = lane & 15;
  const int b = blockIdx.y, t0 = blockIdx.x * 64;
  const int tw0 = t0 + w * 16;
  const int win = *winp;
  int kb_lo = t0 - win;
  if (kb_lo < 0) kb_lo = 0;
  kb_lo &= ~63;

  bf16_8 qf[4];
  const __hip_bfloat16* qb = qr + ((size_t)(b * TT + tw0 + l16)) * 128 + quad * 8;
  #pragma unroll
  for (int kk = 0; kk < 4; ++kk) qf[kk] = *(const bf16_8*)(qb + kk * 32);

  f32x4 o[8] = {};
  float mrow[4] = {-1e30f, -1e30f, -1e30f, -1e30f};
  float lrow[4] = {0.f, 0.f, 0.f, 0.f};
  const float scale = 0.08838834764831845f;  // 1/sqrt(128)

  const int krow_loc = (w * 4) + (lane >> 4);
  const int kc = ((lane & 15) ^ (krow_loc & 15)) << 3;
  const int vloc = lane >> 3;
  const int vc = ((lane & 7) ^ vloc) << 3;

  for (int kb0 = kb_lo; kb0 <= t0; kb0 += 64) {
    const __hip_bfloat16* kbp = kr + ((size_t)(b * TT + kb0)) * 128;
    #pragma unroll
    for (int i = 0; i < 4; ++i) {
      const int krow = i * 16 + krow_loc;
      async16(kbp + (size_t)krow * 128 + kc, &Ksm[i * 2048 + w * 512]);
    }
    #pragma unroll
    for (int i = 0; i < 4; ++i) {
      const int d0 = (i * 4 + w) * 8;
      const int dr = d0 + vloc;
      async16(Vt + ((size_t)(b * 128 + dr)) * TT + kb0 + vc, &Vsm[d0 * 64]);
    }
    __syncthreads();

    f32x4 s[4] = {};
    #pragma unroll
    for (int kk = 0; kk < 4; ++kk) {
      #pragma unroll
      for (int nt = 0; nt < 4; ++nt) {
        const int cc = ((kk * 4 + quad) ^ l16) << 3;
        const bf16_8 bfrag = *(const bf16_8*)&Ksm[(nt * 16 + l16) * 128 + cc];
        s[nt] = __builtin_amdgcn_mfma_f32_16x16x32_bf16(qf[kk], bfrag, s[nt], 0, 0, 0);
      }
    }

    float mb[4] = {-1e30f, -1e30f, -1e30f, -1e30f};
    #pragma unroll
    for (int nt = 0; nt < 4; ++nt) {
      #pragma unroll
      for (int r = 0; r < 4; ++r) {
        const int tq = tw0 + quad * 4 + r;
        const int scol = kb0 + nt * 16 + l16;
        float v = s[nt][r] * scale;
        const bool ok = (scol <= tq) && (tq - scol <= win);
        v = ok ? v : -1e30f;
        s[nt][r] = v;
        mb[r] = fmaxf(mb[r], v);
      }
    }

    #pragma unroll
    for (int r = 0; r < 4; ++r) {
      float m = mb[r];
      m = fmaxf(m, __shfl_xor(m, 1, 16));
      m = fmaxf(m, __shfl_xor(m, 2, 16));
      m = fmaxf(m, __shfl_xor(m, 4, 16));
      m = fmaxf(m, __shfl_xor(m, 8, 16));
      const float mn = fmaxf(mrow[r], m);
      const float alpha = __expf(mrow[r] - mn);
      mrow[r] = mn;
      float rs = 0.f;
      #pragma unroll
      for (int nt = 0; nt < 4; ++nt) {
        const float pv = __expf(s[nt][r] - mn);
        s[nt][r] = pv;
        rs += pv;
      }
      rs += __shfl_xor(rs, 1, 16);
      rs += __shfl_xor(rs, 2, 16);
      rs += __shfl_xor(rs, 4, 16);
      rs += __shfl_xor(rs, 8, 16);
      lrow[r] = lrow[r] * alpha + rs;
      #pragma unroll
      for (int n2 = 0; n2 < 8; ++n2) o[n2][r] *= alpha;
    }

    __hip_bfloat16* pw = &Psm[w * 1152];
    #pragma unroll
    for (int nt = 0; nt < 4; ++nt) {
      #pragma unroll
      for (int r = 0; r < 4; ++r)
        pw[(quad * 4 + r) * 72 + nt * 16 + l16] = __float2bfloat16(s[nt][r]);
    }
    asm volatile("s_waitcnt lgkmcnt(0)" ::: "memory");

    #pragma unroll
    for (int kk2 = 0; kk2 < 2; ++kk2) {
      const bf16_8 pa = *(const bf16_8*)&Psm[w * 1152 + l16 * 72 + kk2 * 32 + quad * 8];
      #pragma unroll
      for (int n2 = 0; n2 < 8; ++n2) {
        const int cc = ((kk2 * 4 + quad) ^ (l16 & 7)) << 3;
        const bf16_8 vb = *(const bf16_8*)&Vsm[(n2 * 16 + l16) * 64 + cc];
        o[n2] = __builtin_amdgcn_mfma_f32_16x16x32_bf16(pa, vb, o[n2], 0, 0, 0);
      }
    }
    __syncthreads();
  }

  #pragma unroll
  for (int n2 = 0; n2 < 8; ++n2) {
    #pragma unroll
    for (int r = 0; r < 4; ++r) {
      const int row = b * TT + tw0 + quad * 4 + r;
      const int col = n2 * 16 + l16;
      y[(size_t)row * 128 + col] = __float2bfloat16(o[n2][r] / lrow[r]);
    }
  }
}

// ---------------- launch ----------------
extern "C" void kernel_launch(void* const* d_in, const int* in_sizes, int n_in,
                              void* d_out, int out_size, void* d_ws, size_t ws_size,
                              hipStream_t stream) {
  const float* x    = (const float*)d_in[0];
  const float* Uq   = (const float*)d_in[1];
  const float* Uk   = (const float*)d_in[2];
  const float* Uv   = (const float*)d_in[3];
  const float* cosb = (const float*)d_in[4];
  const float* sinb = (const float*)d_in[5];
  const float* ln1  = (const float*)d_in[6];
  const float* ln2  = (const float*)d_in[7];
  const float* Wo   = (const float*)d_in[8];
  const float* w1   = (const float*)d_in[9];
  const float* w3   = (const float*)d_in[10];
  const float* w2   = (const float*)d_in[11];
  const int*   winp = (const int*)d_in[12];
  float* out = (float*)d_out;

  uint8_t* p = (uint8_t*)d_ws;
  auto take = [&](size_t bytes) {
    uint8_t* q = p;
    p += (bytes + 255) & ~(size_t)255;
    return q;
  };

  __hip_bfloat16* gb     = (__hip_bfloat16*)take((size_t)BT * DFFC * 2);  // 128 MB
  __hip_bfloat16* normed = (__hip_bfloat16*)take((size_t)BT * DD * 2);    // 32 MB
  __hip_bfloat16* hb     = normed;   // aliased: normed dead after qkv gemm
  __hip_bfloat16* qkv    = (__hip_bfloat16*)take((size_t)BT * 384 * 2);   // 12 MB
  __hip_bfloat16* yb     = qkv;      // aliased: qkv dead after rope+vtrans
  __hip_bfloat16* qr_    = (__hip_bfloat16*)take((size_t)BT * RR * 2);    // 4 MB
  __hip_bfloat16* kr_    = (__hip_bfloat16*)take((size_t)BT * RR * 2);    // 4 MB
  __hip_bfloat16* Vt     = (__hip_bfloat16*)take((size_t)BT * RR * 2);    // 4 MB
  __hip_bfloat16* Ucat   = (__hip_bfloat16*)take((size_t)384 * DD * 2);
  __hip_bfloat16* Wob    = (__hip_bfloat16*)take((size_t)DD * RR * 2);
  __hip_bfloat16* W1b    = (__hip_bfloat16*)take((size_t)DFFC * DD * 2);
  __hip_bfloat16* W3b    = (__hip_bfloat16*)take((size_t)DFFC * DD * 2);
  __hip_bfloat16* W2b    = (__hip_bfloat16*)take((size_t)DD * DFFC * 2);
  float* x_mid = out;  // x_mid lives in d_out (fp32); resid alias is data-dep safe

  // weight converts
  cvt_k<<<128, 256, 0, stream>>>(Uq, Ucat, RR * DD / 4);
  cvt_k<<<128, 256, 0, stream>>>(Uk, Ucat + (size_t)RR * DD, RR * DD / 4);
  cvt_k<<<128, 256, 0, stream>>>(Uv, Ucat + (size_t)2 * RR * DD, RR * DD / 4);
  cvt_k<<<128, 256, 0, stream>>>(Wo, Wob, DD * RR / 4);
  cvt_k<<<4096, 256, 0, stream>>>(w1, W1b, DFFC * DD / 4);
  cvt_k<<<4096, 256, 0, stream>>>(w3, W3b, DFFC * DD / 4);
  cvt_k<<<4096, 256, 0, stream>>>(w2, W2b, DD * DFFC / 4);

  // rmsnorm1
  rmsnorm_k<<<BT, 256, 0, stream>>>(x, ln1, normed);

  // qkv = normed @ Ucat^T   (M=16384, N=384, K=1024)  -- 128^2 kernel (N%256!=0)
  gemm_bt<EPI_BF16><<<dim3(3, 128), 256, 0, stream>>>(normed, Ucat, nullptr, nullptr,
                                                      qkv, nullptr, 384, DD);

  // rope q,k ; transpose v
  rope_k<<<BT * 64 / 256, 256, 0, stream>>>(qkv, cosb, sinb, qr_, kr_);
  vtrans_k<<<dim3(TT / 64, NB), 256, 0, stream>>>(qkv, Vt);

  // attention (writes yb over the dead qkv region)
  attn_k<<<dim3(TT / 64, NB), 256, 0, stream>>>(qr_, kr_, Vt, yb, winp);

  // x_mid = x + y @ Wo^T   (N=1024, K=128)  -> d_out   -- 128^2 kernel (K too short)
  gemm_bt<EPI_RESID><<<dim3(8, 128), 256, 0, stream>>>(yb, Wob, x, nullptr,
                                                       nullptr, x_mid, DD, RR);

  // rmsnorm2 (reads d_out, writes hb over dead normed)
  rmsnorm_k<<<BT, 256, 0, stream>>>(x_mid, ln2, hb);

  // gb = (h @ w1^T) * silu(h @ w3^T)   fused, M=16384 N=4096 K=1024
  gemm_ffn13<<<dim3(DFFC / 128, BT / 256), 512, 0, stream>>>(hb, W1b, W3b, gb,
                                                             DFFC, DD);

  // out = x_mid + g @ w2^T  (N=1024, K=4096)  -- r1 gemm256
  gemm256<EPI_RESID><<<dim3(4, 64), 512, 0, stream>>>(gb, W2b, x_mid, nullptr,
                                                      nullptr, out, DD, DFFC);
}